// Round 3
// baseline (150.068 us; speedup 1.0000x reference)
//
#include <hip/hip_runtime.h>
#include <math.h>

#define NB     8
#define BATCH  64
#define FEAT   512
#define HGT    1024
#define WHALF  513                 // W/2 + 1
#define PIX    (HGT * WHALF)      // 525312  (divisible by 16)
#define TOTAL  (BATCH * PIX)      // 33619968

// sqrtf(0.5f) exactly (f32 nearest of sqrt(0.5)); == reference's radius.max()
#define MAX_R  0x1.6A09E6p-1f

typedef float vfloat4 __attribute__((ext_vector_type(4)));   // clang-native, OK for nontemporal builtins

// ---------------------------------------------------------------------------
// Band classification, bit-exact vs the numpy reference (verified round 1):
//   r2 = u*u + v*v is EXACT in f32 (k^2 + l^2 <= 2^19 fits the mantissa),
//   sqrtf is correctly rounded, boundaries use the identical f32 expression
//   max_r * (i/8).  Returns 8 for the single r == max_r pixel (-> weight 0).
// ---------------------------------------------------------------------------
__device__ __forceinline__ int band_of(int p) {
    const int h  = p / WHALF;
    const int wp = p - h * WHALF;
    const float u = (float)wp * 0.0009765625f;                  // wp / 1024, exact
    const int hv  = (h >= 512) ? (h - 1024) : h;                // fftfreq numerator
    const float v = (float)hv * 0.0009765625f;                  // exact
    const float r = sqrtf(fmaf(u, u, v * v));                   // r2 exact -> r CR

    int j = (int)(r * (8.0f / MAX_R));                          // estimate
    if (j > 8) j = 8;
    const float lo = MAX_R * ((float)j * 0.125f);               // == ref lower[j]
    if (r < lo) {
        --j;
    } else if (j < 8) {
        const float hi = MAX_R * ((float)(j + 1) * 0.125f);     // == ref upper[j]
        if (r >= hi) ++j;
    }
    return j;                                                   // 0..7, or 8 = none
}

// ---------------------------------------------------------------------------
// K1 (fused, independent halves):
//   blocks [0,64)    : bw[b][n] = softmax(ff[b] @ w.T + bias)  (one block/batch)
//   blocks [64,577)  : band[p] for 1024 pixels each (513*1024 == PIX exactly)
// ---------------------------------------------------------------------------
__global__ void __launch_bounds__(256)
prep_kernel(const float* __restrict__ ff,
            const float* __restrict__ w,
            const float* __restrict__ bias,
            float* __restrict__ bw,
            unsigned char* __restrict__ band) {
    const int t = threadIdx.x;

    if (blockIdx.x >= BATCH) {
        // ---- band-map half ----
        const int p = (blockIdx.x - BATCH) * 1024 + t * 4;
        uchar4 o;
        o.x = (unsigned char)band_of(p + 0);
        o.y = (unsigned char)band_of(p + 1);
        o.z = (unsigned char)band_of(p + 2);
        o.w = (unsigned char)band_of(p + 3);
        *reinterpret_cast<uchar4*>(band + p) = o;
        return;
    }

    // ---- matvec + softmax half ----
    const int b = blockIdx.x;
    float part[NB];
#pragma unroll
    for (int n = 0; n < NB; ++n) part[n] = 0.0f;

    for (int k = t; k < FEAT; k += 256) {
        const float f = ff[b * FEAT + k];
#pragma unroll
        for (int n = 0; n < NB; ++n) part[n] += f * w[n * FEAT + k];
    }

#pragma unroll
    for (int n = 0; n < NB; ++n) {
#pragma unroll
        for (int off = 32; off > 0; off >>= 1)
            part[n] += __shfl_down(part[n], off);
    }

    __shared__ float red[4][NB];
    const int wave = t >> 6, lane = t & 63;
    if (lane == 0) {
#pragma unroll
        for (int n = 0; n < NB; ++n) red[wave][n] = part[n];
    }
    __syncthreads();

    if (t == 0) {
        float logit[NB], m = -1e30f;
#pragma unroll
        for (int n = 0; n < NB; ++n) {
            logit[n] = red[0][n] + red[1][n] + red[2][n] + red[3][n] + bias[n];
            m = fmaxf(m, logit[n]);
        }
        float s = 0.0f;
#pragma unroll
        for (int n = 0; n < NB; ++n) { logit[n] = expf(logit[n] - m); s += logit[n]; }
        const float inv = 1.0f / s;
#pragma unroll
        for (int n = 0; n < NB; ++n) bw[b * NB + n] = logit[n] * inv;
    }
}

// ---------------------------------------------------------------------------
// K2: out[b][p] = sbw[b*9 + band[p]], table padded with sbw[b*9+8] = 0.
// Block = (pixel-chunk of 1024, batch-group of 8). Each thread loads its 4
// band bytes ONCE, then emits 8 float4 nontemporal stores (one per batch).
// Band indices are locally constant -> LDS reads are same-address broadcasts.
// ---------------------------------------------------------------------------
__global__ void __launch_bounds__(256)
out_kernel(const float* __restrict__ bw,
           const unsigned char* __restrict__ band,
           float* __restrict__ out) {
    __shared__ float sbw[BATCH * 9];
    for (int i = threadIdx.x; i < BATCH * 9; i += 256) {
        const int b = i / 9, j = i - b * 9;
        sbw[i] = (j < NB) ? bw[b * NB + j] : 0.0f;
    }
    __syncthreads();

    const int chunk = blockIdx.x >> 3;           // 513 pixel-chunks
    const int bg    = blockIdx.x & 7;            // 8 batch-groups
    const int p     = chunk * 1024 + (int)threadIdx.x * 4;

    const uchar4 j4 = *reinterpret_cast<const uchar4*>(band + p);

    float* o = out + (size_t)(bg * 8) * PIX + p;
#pragma unroll
    for (int i = 0; i < 8; ++i) {
        const float* row = sbw + (bg * 8 + i) * 9;
        vfloat4 v;
        v.x = row[j4.x];
        v.y = row[j4.y];
        v.z = row[j4.z];
        v.w = row[j4.w];
        __builtin_nontemporal_store(v, reinterpret_cast<vfloat4*>(o));
        o += PIX;
    }
}

// Fallback if d_ws is somehow too small for bw + band map.
__global__ void __launch_bounds__(256)
out_fused_kernel(const float* __restrict__ bw, float* __restrict__ out) {
    __shared__ float sbw[BATCH * 9];
    for (int i = threadIdx.x; i < BATCH * 9; i += 256) {
        const int b = i / 9, j = i - b * 9;
        sbw[i] = (j < NB) ? bw[b * NB + j] : 0.0f;
    }
    __syncthreads();

    const int nq = TOTAL / 4;
    const int stride = gridDim.x * blockDim.x;
    for (int q = blockIdx.x * blockDim.x + threadIdx.x; q < nq; q += stride) {
        const int base = q * 4;
        const int b = base / PIX;
        const int p = base - b * PIX;
        const float* row = sbw + b * 9;
        float4 o;
        o.x = row[band_of(p + 0)];
        o.y = row[band_of(p + 1)];
        o.z = row[band_of(p + 2)];
        o.w = row[band_of(p + 3)];
        reinterpret_cast<float4*>(out)[q] = o;
    }
}

extern "C" void kernel_launch(void* const* d_in, const int* in_sizes, int n_in,
                              void* d_out, int out_size, void* d_ws, size_t ws_size,
                              hipStream_t stream) {
    const float* ff   = (const float*)d_in[0];   // [64, 512]
    const float* w    = (const float*)d_in[1];   // [8, 512]
    const float* bias = (const float*)d_in[2];   // [8]
    float* out = (float*)d_out;                  // [64, 1, 1024, 513] f32

    float* bw = (float*)d_ws;                                    // 2048 B
    unsigned char* band = (unsigned char*)d_ws + 2048;           // 525312 B

    if (ws_size >= 2048 + (size_t)PIX) {
        prep_kernel<<<BATCH + PIX / 1024, 256, 0, stream>>>(ff, w, bias, bw, band);
        out_kernel<<<(PIX / 1024) * 8, 256, 0, stream>>>(bw, band, out);
    } else {
        prep_kernel<<<BATCH, 256, 0, stream>>>(ff, w, bias, bw, band);  // bw half only
        out_fused_kernel<<<2048, 256, 0, stream>>>(bw, out);
    }
}